// Round 13
// baseline (1814.804 us; speedup 1.0000x reference)
//
#include <hip/hip_runtime.h>
#include <hip/hip_bf16.h>
#include <math.h>

// ---------------------------------------------------------------------------
// MoE block: router + grouped-expert SwiGLU + shared SwiGLU MLP.
// Round 13: R12 GEMM core unchanged; overhead attack:
//  - merged GEMM dispatches (expert+shared in one launch via flagged tiles)
//  - vectorized 64x64 transpose (float4 in, bf16x8 out)
//  - convert_x fused into router
// ---------------------------------------------------------------------------

typedef __bf16 bf16_t;
typedef __bf16 bf16x8 __attribute__((ext_vector_type(8)));
typedef float  f32x4  __attribute__((ext_vector_type(4)));

constexpr int NTOK = 8192;          // B*S
constexpr int D    = 2048;
constexpr int E    = 32;
constexpr int I    = 1024;
constexpr int TK   = 8;             // TOP_K
constexpr int NK   = NTOK * TK;     // 65536 slots
constexpr int TM   = 256;           // GEMM row tile
constexpr int MAX_TILES  = E + NK / TM;          // 288 worst-case expert tiles
constexpr int MAX_TILES2 = MAX_TILES + NTOK/TM;  // +32 shared tiles = 320 (div 8)
constexpr float RSCALE = 2.5f;

#define GL16(g, l) __builtin_amdgcn_global_load_lds( \
    (const __attribute__((address_space(1))) void*)(g), \
    (__attribute__((address_space(3))) void*)(l), 16, 0, 0)

// ------------------------------- utilities --------------------------------

__global__ __launch_bounds__(64) void k_zero_meta(int* counts, int* cursors, int* ntl) {
    int t = threadIdx.x;
    if (t < E) { counts[t] = 0; cursors[t] = 0; }
    if (t == 0) *ntl = 0;
}

__global__ __launch_bounds__(64) void k_sentinel(float* out) {
    if (threadIdx.x == 0) out[0] = 12345.0f;   // signals ws_size too small
}

// 64x64-tile transpose+convert: src [b][R][C] f32 -> dst [b][rc(C)][R] bf16
// MODE 0: rc=c | 1: gate/up interleave (c<I ? 2c : 2(c-I)+1) | 2: rc=2c | 3: rc=2c+1
template <int MODE>
__global__ __launch_bounds__(256) void k_transpose64(const float* __restrict__ src,
                                                     bf16_t* __restrict__ dst,
                                                     int R, int C,
                                                     size_t srcMat, size_t dstMat) {
    __shared__ float t[64][65];
    int b = blockIdx.z;
    const float* s = src + (size_t)b * srcMat;
    bf16_t* d = dst + (size_t)b * dstMat;
    int c0 = blockIdx.x * 64, r0 = blockIdx.y * 64;
    int tid = threadIdx.x;
    int rr = tid >> 4, c4 = (tid & 15) * 4;
#pragma unroll
    for (int yy = 0; yy < 4; yy++) {
        int r = yy * 16 + rr;
        float4 v = *(const float4*)(s + (size_t)(r0 + r) * C + c0 + c4);
        t[r][c4] = v.x; t[r][c4 + 1] = v.y; t[r][c4 + 2] = v.z; t[r][c4 + 3] = v.w;
    }
    __syncthreads();
    int j = tid & 7, ccb = tid >> 3;    // j: 8-row chunk, ccb: 0..31
#pragma unroll
    for (int zz = 0; zz < 2; zz++) {
        int c = c0 + zz * 32 + ccb;
        int rc = (MODE == 0) ? c
               : (MODE == 1) ? ((c < I) ? 2 * c : 2 * (c - I) + 1)
               : (MODE == 2) ? 2 * c : 2 * c + 1;
        bf16_t tmp[8];
#pragma unroll
        for (int i = 0; i < 8; i++) tmp[i] = (bf16_t)t[j * 8 + i][zz * 32 + ccb];
        *(uint4*)(d + (size_t)rc * R + r0 + j * 8) = *(const uint4*)tmp;
    }
}

// ------------------------------- router -----------------------------------
// also converts this token's x row to bf16 (fused convert_x)

__global__ __launch_bounds__(256) void k_router(const float* __restrict__ x,
                                                const float* __restrict__ gw,
                                                const float* __restrict__ eb,
                                                bf16_t* __restrict__ xb,
                                                float* __restrict__ out_idx,
                                                float* __restrict__ out_scores,
                                                float* __restrict__ topk_w,
                                                int* __restrict__ tok_expert,
                                                int* __restrict__ counts) {
    int t = blockIdx.x;
    int tid = threadIdx.x;
    const float* xr = x + (size_t)t * D;

    // fused f32->bf16 conversion of this row (8 elems/thread)
    {
        int c = tid * 8;
        float4 a = *(const float4*)(xr + c), b2 = *(const float4*)(xr + c + 4);
        bf16_t tmp[8] = {(bf16_t)a.x, (bf16_t)a.y, (bf16_t)a.z, (bf16_t)a.w,
                         (bf16_t)b2.x, (bf16_t)b2.y, (bf16_t)b2.z, (bf16_t)b2.w};
        *(uint4*)(xb + (size_t)t * D + c) = *(const uint4*)tmp;
    }

    int e = tid & 31, part = tid >> 5;         // 8 parts x 256 d each
    float partial = 0.f;
    int d0 = part * 256;
    for (int d = d0; d < d0 + 256; d++)
        partial += xr[d] * gw[(size_t)d * E + e];

    __shared__ float red[8][32];
    __shared__ float sc[32], sfr[32];
    red[part][e] = partial;
    __syncthreads();
    if (tid < 32) {
        float l = 0.f;
#pragma unroll
        for (int p = 0; p < 8; p++) l += red[p][tid];
        float s = 1.f / (1.f + expf(-l));
        sc[tid] = s;
        sfr[tid] = s + eb[tid];
        out_scores[(size_t)t * E + tid] = s;
    }
    __syncthreads();
    if (tid == 0) {
        float gs[8];
#pragma unroll
        for (int g = 0; g < 8; g++) {
            float m1 = -1e30f, m2 = -1e30f;
#pragma unroll
            for (int i = 0; i < 4; i++) {
                float v = sfr[g * 4 + i];
                if (v > m1) { m2 = m1; m1 = v; } else if (v > m2) m2 = v;
            }
            gs[g] = m1 + m2;
        }
        bool gsel[8] = {false, false, false, false, false, false, false, false};
        for (int it = 0; it < 4; it++) {
            int bi = -1; float bv = -1e30f;
            for (int g = 0; g < 8; g++)
                if (!gsel[g] && gs[g] > bv) { bv = gs[g]; bi = g; }
            gsel[bi] = true;
        }
        float masked[32];
        for (int i = 0; i < 32; i++) masked[i] = gsel[i >> 2] ? sfr[i] : -1e30f;
        int idx[TK]; float w[TK]; float wsum = 0.f;
        for (int k = 0; k < TK; k++) {
            int bi = 0; float bv = -1e30f;
            for (int i = 0; i < 32; i++)
                if (masked[i] > bv) { bv = masked[i]; bi = i; }
            masked[bi] = -1e30f;
            idx[k] = bi; w[k] = sc[bi]; wsum += w[k];
        }
        float inv = RSCALE / (wsum + 1e-20f);
        for (int k = 0; k < TK; k++) {
            out_idx[(size_t)t * TK + k] = (float)idx[k];
            topk_w[(size_t)t * TK + k] = w[k] * inv;
            tok_expert[(size_t)t * TK + k] = idx[k];
            atomicAdd(&counts[idx[k]], 1);
        }
    }
}

// expert tiles [0,ne) flag=0, then 32 shared tiles flag=1; *ntl = total
__global__ __launch_bounds__(64) void k_offsets(const int* __restrict__ counts,
                                                int* __restrict__ offs,
                                                int4* __restrict__ ttbl,
                                                int* __restrict__ ntl) {
    if (threadIdx.x != 0) return;
    int off = 0, nt = 0;
    for (int e = 0; e < E; e++) {
        offs[e] = off;
        int c = counts[e];
        for (int r = 0; r < c; r += TM) {
            ttbl[nt] = make_int4(off + r, min(TM, c - r), e, 0);
            nt++;
        }
        off += c;
    }
    offs[E] = off;
    for (int i = 0; i < NTOK / TM; i++) {
        ttbl[nt] = make_int4(i * TM, TM, 0, 1);
        nt++;
    }
    *ntl = nt;
}

__global__ __launch_bounds__(256) void k_scatter(const int* __restrict__ tok_expert,
                                                 const int* __restrict__ offs,
                                                 int* __restrict__ cursors,
                                                 int* __restrict__ slot_token,
                                                 int* __restrict__ slot_inv) {
    int i = blockIdx.x * 256 + threadIdx.x;
    if (i >= NK) return;
    int e = tok_expert[i];
    int pos = offs[e] + atomicAdd(&cursors[e], 1);
    slot_token[pos] = i >> 3;   // TK = 8
    slot_inv[i] = pos;
}

// --------------------- 256x256 8-phase pipelined GEMM ----------------------
// R12 core (single aF set + WAR-safe refill interleave, SGB-pinned,
// vmcnt(4)/phase, XOR-swizzled LDS, XCD-chunked block swizzle).
// Merged dispatch: per-tile flag selects expert vs shared A/B/C.

#define SCB() __builtin_amdgcn_sched_barrier(0)
#define SG(m, n) __builtin_amdgcn_sched_group_barrier(m, n, 0)
#define SG_PLAIN() do { SG(0x30, 2); SG(0x8, 16); } while (0)
#define SG_PRE()   do { SG(0x100, 4); SG(0x30, 2); SG(0x8, 16); } while (0)
#define SG_RF()    do { SG(0x30, 2); SG(0x8, 4); SG(0x100, 2); SG(0x8, 4); \
    SG(0x100, 2); SG(0x8, 4); SG(0x100, 2); SG(0x8, 4); SG(0x100, 2); } while (0)
#define SG_PRERF() do { SG(0x100, 4); SG(0x30, 2); SG(0x8, 4); SG(0x100, 2); \
    SG(0x8, 4); SG(0x100, 2); SG(0x8, 4); SG(0x100, 2); SG(0x8, 4); SG(0x100, 2); } while (0)

#define PEND() do { asm volatile("s_waitcnt vmcnt(4)" ::: "memory"); \
    __builtin_amdgcn_s_barrier(); SCB(); } while (0)

#define SA2(b, rnd, k0) do { \
    GL16(gA[0][rnd] + (k0), smb + (b) * 65536 + (rnd) * 8192 + w * 1024); \
    GL16(gA[1][rnd] + (k0), smb + (b) * 65536 + 16384 + (rnd) * 8192 + w * 1024); } while (0)

#define SB(b, h, k0) do { \
    GL16(gB[h][0] + (k0), smb + (b) * 65536 + 32768 + (h) * 16384 + w * 1024); \
    GL16(gB[h][1] + (k0), smb + (b) * 65536 + 32768 + (h) * 16384 + 8192 + w * 1024); } while (0)

#define LDA(b, mh) do { _Pragma("unroll") for (int m_ = 0; m_ < 4; m_++) { \
    aF[m_][0] = *(const bf16x8*)(smb + (b) * 65536 + wm * 16384 + (mh) * 8192 + m_ * 2048 + lofs0); \
    aF[m_][1] = *(const bf16x8*)(smb + (b) * 65536 + wm * 16384 + (mh) * 8192 + m_ * 2048 + lofs1); } } while (0)

#define LDB(dst, b, nh) do { _Pragma("unroll") for (int n_ = 0; n_ < 2; n_++) { \
    dst[n_][0] = *(const bf16x8*)(smb + (b) * 65536 + 32768 + wn * 8192 + (nh) * 4096 + n_ * 2048 + lofs0); \
    dst[n_][1] = *(const bf16x8*)(smb + (b) * 65536 + 32768 + wn * 8192 + (nh) * 4096 + n_ * 2048 + lofs1); } } while (0)

#define MMA(bv, MH, NH) do { \
    __builtin_amdgcn_s_setprio(1); \
    _Pragma("unroll") for (int m_ = 0; m_ < 4; m_++) \
    _Pragma("unroll") for (int n_ = 0; n_ < 2; n_++) { \
    acc[(MH) * 4 + m_][(NH) * 2 + n_] = __builtin_amdgcn_mfma_f32_16x16x32_bf16( \
        aF[m_][0], bv[n_][0], acc[(MH) * 4 + m_][(NH) * 2 + n_], 0, 0, 0); \
    acc[(MH) * 4 + m_][(NH) * 2 + n_] = __builtin_amdgcn_mfma_f32_16x16x32_bf16( \
        aF[m_][1], bv[n_][1], acc[(MH) * 4 + m_][(NH) * 2 + n_], 0, 0, 0); } \
    __builtin_amdgcn_s_setprio(0); } while (0)

#define MMARF(bv, MH, NH, rb, rmh) do { \
    __builtin_amdgcn_s_setprio(1); \
    _Pragma("unroll") for (int m_ = 0; m_ < 4; m_++) { \
    _Pragma("unroll") for (int n_ = 0; n_ < 2; n_++) { \
    acc[(MH) * 4 + m_][(NH) * 2 + n_] = __builtin_amdgcn_mfma_f32_16x16x32_bf16( \
        aF[m_][0], bv[n_][0], acc[(MH) * 4 + m_][(NH) * 2 + n_], 0, 0, 0); \
    acc[(MH) * 4 + m_][(NH) * 2 + n_] = __builtin_amdgcn_mfma_f32_16x16x32_bf16( \
        aF[m_][1], bv[n_][1], acc[(MH) * 4 + m_][(NH) * 2 + n_], 0, 0, 0); } \
    aF[m_][0] = *(const bf16x8*)(smb + (rb) * 65536 + wm * 16384 + (rmh) * 8192 + m_ * 2048 + lofs0); \
    aF[m_][1] = *(const bf16x8*)(smb + (rb) * 65536 + wm * 16384 + (rmh) * 8192 + m_ * 2048 + lofs1); } \
    __builtin_amdgcn_s_setprio(0); } while (0)

// GEMM=1: A=xb (gather for expert tiles), B=gut/sh1t, C=inter/inter_s, EPI SwiGLU
// GEMM=2: A=inter/inter_s, B=dnt/sdt, C=outS(bf16)/out(f32)
template <int GEMM>
__global__ __launch_bounds__(512, 2) void k_mm8(const bf16_t* __restrict__ Ae,
                                                const bf16_t* __restrict__ Ash,
                                                const bf16_t* __restrict__ Be,
                                                const bf16_t* __restrict__ Bs,
                                                int K, size_t estride,
                                                const int* __restrict__ slot_token,
                                                const int4* __restrict__ ttbl,
                                                const int* __restrict__ ntl,
                                                void* __restrict__ Ce,
                                                void* __restrict__ Cs, int ldc) {
    // XCD-chunked swizzle (grid.y divisible by 8)
    int L = (int)blockIdx.y * 8 + (int)blockIdx.x;
    int xcd = L & 7, k = L >> 3;
    int per = (int)gridDim.y >> 3;
    int ty = xcd * per + (k >> 3);
    int tx = k & 7;

    if (ty >= *ntl) return;
    int4 tt = ttbl[ty];
    int base_slot = tt.x, rows = tt.y, e = tt.z, flag = tt.w;
    const bf16_t* A = flag ? Ash : Ae;
    bool gather = (GEMM == 1) && !flag;

    int c0 = tx * 256;
    const bf16_t* Bw = (flag ? Bs : Be + (size_t)e * estride) + (size_t)c0 * K;

    extern __shared__ char smb[];   // 128 KiB: [2][A 32K | B 32K]

    int tid = threadIdx.x, lane = tid & 63, w = tid >> 6;
    int wm = w >> 2, wn = w & 3;
    int lr = lane & 15, hi = lane >> 4;
    int rx = lr & 7;
    int lofs0 = lr * 128 + ((hi ^ rx) << 4);
    int lofs1 = lr * 128 + (((4 + hi) ^ rx) << 4);

    int srow = tid >> 3;
    int cbg = (tid & 7) ^ (srow & 7);
    const bf16_t* gA[2][2]; const bf16_t* gB[2][2];
#pragma unroll
    for (int h = 0; h < 2; h++)
#pragma unroll
        for (int rnd = 0; rnd < 2; rnd++) {
            int r = h * 128 + rnd * 64 + srow;
            int ar = min(r, rows - 1);
            int tok = gather ? slot_token[base_slot + ar] : (base_slot + ar);
            gA[h][rnd] = A + (size_t)tok * K + cbg * 8;
            gB[h][rnd] = Bw + (size_t)r * K + cbg * 8;
        }

    f32x4 acc[8][4] = {};
    bf16x8 aF[4][2], b0[2][2], b1[2][2];

    SA2(0, 0, 0); SA2(0, 1, 0);
    SB(0, 0, 0); SB(0, 1, 0);
    SA2(1, 0, 64);
    SB(1, 0, 64); SB(1, 1, 64);
    asm volatile("s_waitcnt vmcnt(0)" ::: "memory");
    __builtin_amdgcn_s_barrier();
    SCB();
    LDA(0, 0); LDB(b0, 0, 0);

    int nt = K >> 6;                 // K/64, even (16 or 32)
    for (int kt = 0; kt < nt; kt += 2) {
        int k1 = (kt + 1) << 6;
        int k2 = (kt + 2 < nt) ? (kt + 2) << 6 : 0;   // wrapped, never consumed
        int k3 = (kt + 3 < nt) ? (kt + 3) << 6 : 0;
        // P1
        LDB(b1, 0, 1);
        SA2(1, 1, k1);
        MMA(b0, 0, 0);
        SG_PRE(); PEND();
        // P2
        SA2(0, 0, k2);
        MMARF(b1, 0, 1, 0, 1);
        SG_RF(); PEND();
        // P3
        SB(0, 0, k2);
        MMA(b0, 1, 0);
        SG_PLAIN(); PEND();
        // P4
        LDB(b0, 1, 0);
        SB(0, 1, k2);
        MMARF(b1, 1, 1, 1, 0);
        SG_PRERF(); PEND();
        // P5
        LDB(b1, 1, 1);
        SA2(0, 1, k2);
        MMA(b0, 0, 0);
        SG_PRE(); PEND();
        // P6
        SA2(1, 0, k3);
        MMARF(b1, 0, 1, 1, 1);
        SG_RF(); PEND();
        // P7
        SB(1, 0, k3);
        MMA(b0, 1, 0);
        SG_PLAIN(); PEND();
        // P8
        LDB(b0, 0, 0);
        SB(1, 1, k3);
        MMARF(b1, 1, 1, 0, 0);
        SG_PRERF(); PEND();
    }

    // epilogue: C row r = wm*128 + mi*16 + hi*4 + j, col = c0 + wn*64 + f*16 + lr
#pragma unroll
    for (int mi = 0; mi < 8; mi++) {
#pragma unroll
        for (int j = 0; j < 4; j++) {
            int r = wm * 128 + mi * 16 + hi * 4 + j;
            bool valid = (r < rows);
            size_t orow = (size_t)base_slot + r;
#pragma unroll
            for (int f = 0; f < 4; f++) {
                float v = acc[mi][f][j];
                int c = c0 + wn * 64 + f * 16 + lr;
                if (GEMM == 1) {
                    float o = __shfl_xor(v, 1);
                    float g = (lane & 1) ? o : v;
                    float u = (lane & 1) ? v : o;
                    float sv = g / (1.f + __expf(-g)) * u;
                    bf16_t* Cp = (bf16_t*)(flag ? Cs : Ce);
                    if (valid && !(lane & 1))
                        Cp[orow * ldc + (c >> 1)] = (bf16_t)sv;
                } else {
                    if (flag) {
                        if (valid) ((float*)Cs)[orow * ldc + c] = v;
                    } else {
                        float o = __shfl_xor(v, 1);
                        if (valid && !(lane & 1)) {
                            bf16_t pr[2] = {(bf16_t)v, (bf16_t)o};
                            *(unsigned int*)((bf16_t*)Ce + orow * ldc + c) = *(unsigned int*)pr;
                        }
                    }
                }
            }
        }
    }
}

// ------------------------------- finalize ----------------------------------
// out[tok][d] += sum_k w_k * outS[pos(tok,k)][d]   (out already = shared MLP)

__global__ __launch_bounds__(256) void k_finalize(const bf16_t* __restrict__ outS,
                                                  const int* __restrict__ slot_inv,
                                                  const float* __restrict__ tkw,
                                                  float* __restrict__ out) {
    int tok = blockIdx.x, tid = threadIdx.x;
    __shared__ int sp[TK];
    __shared__ float swt[TK];
    if (tid < TK) {
        sp[tid] = slot_inv[tok * TK + tid];
        swt[tid] = tkw[tok * TK + tid];
    }
    __syncthreads();
    int c = tid * 8;                 // 2048 / 256
    float* op = out + (size_t)tok * D + c;
    float acc[8];
    float4 o0 = *(float4*)op, o1 = *(float4*)(op + 4);
    acc[0] = o0.x; acc[1] = o0.y; acc[2] = o0.z; acc[3] = o0.w;
    acc[4] = o1.x; acc[5] = o1.y; acc[6] = o1.z; acc[7] = o1.w;
#pragma unroll
    for (int k = 0; k < TK; k++) {
        bf16x8 v = *(const bf16x8*)(outS + (size_t)sp[k] * D + c);
        float w = swt[k];
#pragma unroll
        for (int j = 0; j < 8; j++) acc[j] += w * (float)v[j];
    }
    o0 = make_float4(acc[0], acc[1], acc[2], acc[3]);
    o1 = make_float4(acc[4], acc[5], acc[6], acc[7]);
    *(float4*)op = o0;
    *(float4*)(op + 4) = o1;
}

// ------------------------------- launcher ---------------------------------

extern "C" void kernel_launch(void* const* d_in, const int* in_sizes, int n_in,
                              void* d_out, int out_size, void* d_ws, size_t ws_size,
                              hipStream_t stream) {
    const float* x  = (const float*)d_in[0];
    const float* gw = (const float*)d_in[1];
    const float* eb = (const float*)d_in[2];
    const float* gu = (const float*)d_in[3];
    const float* dn = (const float*)d_in[4];
    const float* sg = (const float*)d_in[5];
    const float* su = (const float*)d_in[6];
    const float* sd = (const float*)d_in[7];

    float* out        = (float*)d_out;
    float* out_idx    = out + (size_t)NTOK * D;
    float* out_scores = out_idx + (size_t)NTOK * TK;

    char* w = (char*)d_ws;
    auto alloc = [&](size_t bytes) {
        char* p = w;
        w += (bytes + 255) & ~(size_t)255;
        return p;
    };
    bf16_t* xb      = (bf16_t*)alloc((size_t)NTOK * D * 2);
    bf16_t* gut     = (bf16_t*)alloc((size_t)E * 2 * I * D * 2);   // [E][2I][D] interleaved
    bf16_t* dnt     = (bf16_t*)alloc((size_t)E * D * I * 2);       // [E][D][I]
    bf16_t* sh1t    = (bf16_t*)alloc((size_t)2 * I * D * 2);       // [2I][D] interleaved
    bf16_t* sdt     = (bf16_t*)alloc((size_t)D * I * 2);           // [D][I]
    bf16_t* inter   = (bf16_t*)alloc((size_t)NK * I * 2);
    bf16_t* inter_s = (bf16_t*)alloc((size_t)NTOK * I * 2);
    float*  tkw     = (float*)alloc((size_t)NK * 4);
    int*    tke     = (int*)alloc((size_t)NK * 4);
    int*    stok    = (int*)alloc((size_t)NK * 4);
    int*    sinv    = (int*)alloc((size_t)NK * 4);
    int*    counts  = (int*)alloc(E * 4);
    int*    offs    = (int*)alloc((E + 1) * 4);
    int*    curs    = (int*)alloc(E * 4);
    int4*   ttbl    = (int4*)alloc(MAX_TILES2 * 16);
    int*    ntl     = (int*)alloc(4);
    // outS[NK][D] bf16 (256MB) aliases gut (256MB): gut is dead after expert gemm1
    bf16_t* outS    = gut;

    if ((size_t)(w - (char*)d_ws) > ws_size) {
        k_sentinel<<<1, 64, 0, stream>>>(out);
        return;
    }

    k_zero_meta<<<1, 64, 0, stream>>>(counts, curs, ntl);

    // weight reshapes (64x64 vectorized transpose)
    k_transpose64<1><<<dim3(2 * I / 64, D / 64, E), 256, 0, stream>>>(
        gu, gut, D, 2 * I, (size_t)D * 2 * I, (size_t)D * 2 * I);
    k_transpose64<0><<<dim3(D / 64, I / 64, E), 256, 0, stream>>>(
        dn, dnt, I, D, (size_t)I * D, (size_t)I * D);
    k_transpose64<2><<<dim3(I / 64, D / 64, 1), 256, 0, stream>>>(
        sg, sh1t, D, I, 0, 0);
    k_transpose64<3><<<dim3(I / 64, D / 64, 1), 256, 0, stream>>>(
        su, sh1t, D, I, 0, 0);
    k_transpose64<0><<<dim3(D / 64, I / 64, 1), 256, 0, stream>>>(
        sd, sdt, I, D, 0, 0);

    // routing (+ fused x->bf16 conversion)
    k_router<<<NTOK, 256, 0, stream>>>(x, gw, eb, xb, out_idx, out_scores, tkw, tke, counts);
    k_offsets<<<1, 64, 0, stream>>>(counts, offs, ttbl, ntl);
    k_scatter<<<NK / 256, 256, 0, stream>>>(tke, offs, curs, stok, sinv);

    constexpr size_t SMEM = 131072;
    // merged gemm1 (expert + shared); must finish before outS overwrites gut
    k_mm8<1><<<dim3(8, MAX_TILES2), 512, SMEM, stream>>>(
        xb, xb, gut, sh1t, D, (size_t)2 * I * D, stok, ttbl, ntl, inter, inter_s, I);
    // merged gemm2 (expert -> outS bf16, shared -> out f32)
    k_mm8<2><<<dim3(8, MAX_TILES2), 512, SMEM, stream>>>(
        inter, inter_s, dnt, sdt, I, (size_t)D * I, stok, ttbl, ntl, outS, out, D);

    // combine
    k_finalize<<<NTOK, 256, 0, stream>>>(outS, sinv, tkw, out);
}